// Round 11
// baseline (129.864 us; speedup 1.0000x reference)
//
#include <hip/hip_runtime.h>
#include <hip/hip_bf16.h>

#define NB 4
#define NC 48
#define H0 512
#define W0 512
#define HW (H0 * W0)
#define NCH 17   // 1 intensity + 16 mueller
#define OUTC 51  // 17 * 3 levels
#define TW 64    // tile width  (one wave row = one 1KB DMA per channel)
#define TH 4     // tile height (= pool window height)
#define SROW 260 // LDS row stride in floats: 1040B = 16B-aligned, +4 bank stagger

typedef const float __attribute__((address_space(1))) f32g;
typedef float __attribute__((address_space(3))) f32l;

// ---------------------------------------------------------------------------
// 4x4 inverse via adjugate (row-major).
// ---------------------------------------------------------------------------
__device__ __forceinline__ void inv4x4(const float* m, float* o) {
    float inv[16];
    inv[0]  =  m[5]*m[10]*m[15] - m[5]*m[11]*m[14] - m[9]*m[6]*m[15] + m[9]*m[7]*m[14] + m[13]*m[6]*m[11] - m[13]*m[7]*m[10];
    inv[4]  = -m[4]*m[10]*m[15] + m[4]*m[11]*m[14] + m[8]*m[6]*m[15] - m[8]*m[7]*m[14] - m[12]*m[6]*m[11] + m[12]*m[7]*m[10];
    inv[8]  =  m[4]*m[9]*m[15]  - m[4]*m[11]*m[13] - m[8]*m[5]*m[15] + m[8]*m[7]*m[13] + m[12]*m[5]*m[11] - m[12]*m[7]*m[9];
    inv[12] = -m[4]*m[9]*m[14]  + m[4]*m[10]*m[13] + m[8]*m[5]*m[14] - m[8]*m[6]*m[13] - m[12]*m[5]*m[10] + m[12]*m[6]*m[9];
    inv[1]  = -m[1]*m[10]*m[15] + m[1]*m[11]*m[14] + m[9]*m[2]*m[15] - m[9]*m[3]*m[14] - m[13]*m[2]*m[11] + m[13]*m[3]*m[10];
    inv[5]  =  m[0]*m[10]*m[15] - m[0]*m[11]*m[14] - m[8]*m[2]*m[15] + m[8]*m[3]*m[14] + m[12]*m[2]*m[11] - m[12]*m[3]*m[10];
    inv[9]  = -m[0]*m[9]*m[15]  + m[0]*m[11]*m[13] + m[8]*m[1]*m[15] - m[8]*m[3]*m[13] - m[12]*m[1]*m[11] + m[12]*m[3]*m[9];
    inv[13] =  m[0]*m[9]*m[14]  - m[0]*m[10]*m[13] - m[8]*m[1]*m[14] + m[8]*m[2]*m[13] + m[12]*m[1]*m[10] - m[12]*m[2]*m[9];
    inv[2]  =  m[1]*m[6]*m[15]  - m[1]*m[7]*m[14]  - m[5]*m[2]*m[15] + m[5]*m[3]*m[14] + m[13]*m[2]*m[7]  - m[13]*m[3]*m[6];
    inv[6]  = -m[0]*m[6]*m[15]  + m[0]*m[7]*m[14]  + m[4]*m[2]*m[15] - m[4]*m[3]*m[14] - m[12]*m[2]*m[7]  + m[12]*m[3]*m[6];
    inv[10] =  m[0]*m[5]*m[15]  - m[0]*m[7]*m[13]  - m[4]*m[1]*m[15] + m[4]*m[3]*m[13] + m[12]*m[1]*m[7]  - m[12]*m[3]*m[5];
    inv[14] = -m[0]*m[5]*m[14]  + m[0]*m[6]*m[13]  + m[4]*m[1]*m[14] - m[4]*m[2]*m[13] - m[12]*m[1]*m[6]  + m[12]*m[2]*m[5];
    inv[3]  = -m[1]*m[6]*m[11]  + m[1]*m[7]*m[10]  + m[5]*m[2]*m[11] - m[5]*m[3]*m[10] - m[9]*m[2]*m[7]   + m[9]*m[3]*m[6];
    inv[7]  =  m[0]*m[6]*m[11]  - m[0]*m[7]*m[10]  - m[4]*m[2]*m[11] + m[4]*m[3]*m[10] + m[8]*m[2]*m[7]   - m[8]*m[3]*m[6];
    inv[11] = -m[0]*m[5]*m[11]  + m[0]*m[7]*m[9]   + m[4]*m[1]*m[11] - m[4]*m[3]*m[9]  - m[8]*m[1]*m[7]   + m[8]*m[3]*m[5];
    inv[15] =  m[0]*m[5]*m[10]  - m[0]*m[6]*m[9]   - m[4]*m[1]*m[10] + m[4]*m[2]*m[9]  + m[8]*m[1]*m[6]   - m[8]*m[2]*m[5];
    float det = m[0]*inv[0] + m[1]*inv[4] + m[2]*inv[8] + m[3]*inv[12];
    float rd = 1.0f / det;
    #pragma unroll
    for (int i = 0; i < 16; i++) o[i] = inv[i] * rd;
}

// ---------------------------------------------------------------------------
// Fused Mueller features + optional 4x4 maxpool, 3-phase LDS (16ch at a time).
// (Round-9 structure, unchanged: best measured = 113.9 us total.)
// ---------------------------------------------------------------------------
template <bool POOL>
__global__ __launch_bounds__(256, 8) void feat_pool_lds(
        const float* __restrict__ in, float* __restrict__ featout,
        float* __restrict__ poolout, int h, int w, int cpb) {
    __shared__ float s[16][SROW];

    int tilesX = w / TW;
    int tilesY = h / TH;
    int tile = blockIdx.x;
    int b = tile / (tilesX * tilesY);
    int trem = tile - b * (tilesX * tilesY);
    int tileY = trem / tilesX;
    int tileX = trem - tileY * tilesX;

    int tid = threadIdx.x;
    int ly = tid >> 6;          // wave id 0..3
    int lx = tid & 63;          // lane 0..63
    int hw = h * w;
    int ho = h >> 2, wo = w >> 2;

    // per-lane DMA source: lane l covers tile row (l>>4), cols (l&15)*4 .. +3
    const float* dmasrc = in + (size_t)b * NC * hw
                        + (size_t)(tileY * TH + (lx >> 4)) * w
                        + tileX * TW + (lx & 15) * 4;

    auto STAGE = [&](int ch0) {
        #pragma unroll
        for (int kk = 0; kk < 4; kk++) {
            int k = ly * 4 + kk;
            __builtin_amdgcn_global_load_lds((f32g*)(dmasrc + (size_t)(ch0 + k) * hw),
                                             (f32l*)&s[k][0], 16, 0, 0);
        }
    };
    auto POOLG = [&](int ch0) {
        if (POOL) {
            int k = tid >> 4;
            int c = tid & 15;
            float m = -INFINITY;
            #pragma unroll
            for (int r = 0; r < TH; r++)
                #pragma unroll
                for (int j = 0; j < 4; j++)
                    m = fmaxf(m, s[k][r * TW + c * 4 + j]);
            poolout[((size_t)(b * NC + ch0 + k) * ho + tileY) * wo + tileX * 16 + c] = m;
        }
    };

    float tmp[16];

    // ---- phase 1: W -> iW ----
    STAGE(32);
    __syncthreads();
    POOLG(32);
    float iW[16];
    #pragma unroll
    for (int k = 0; k < 16; k++) tmp[k] = s[k][tid];
    inv4x4(tmp, iW);
    __syncthreads();

    // ---- phase 2: I -> P = I*iW, intensity ----
    STAGE(0);
    __syncthreads();
    POOLG(0);
    float P[16];
    float inten = 0.f;
    #pragma unroll
    for (int r = 0; r < 4; r++) {
        float i0 = s[r * 4 + 0][tid], i1 = s[r * 4 + 1][tid],
              i2 = s[r * 4 + 2][tid], i3 = s[r * 4 + 3][tid];
        inten += i0 + i1 + i2 + i3;
        #pragma unroll
        for (int c = 0; c < 4; c++)
            P[r * 4 + c] = i0 * iW[0 * 4 + c] + i1 * iW[1 * 4 + c] +
                           i2 * iW[2 * 4 + c] + i3 * iW[3 * 4 + c];
    }
    inten *= (1.0f / 16.0f);
    __syncthreads();

    // ---- phase 3: A -> iA, M = iA*P, store ----
    STAGE(16);
    __syncthreads();
    POOLG(16);
    float iA[16];
    #pragma unroll
    for (int k = 0; k < 16; k++) tmp[k] = s[k][tid];
    inv4x4(tmp, iA);

    float M[16];
    #pragma unroll
    for (int r = 0; r < 4; r++)
        #pragma unroll
        for (int c = 0; c < 4; c++)
            M[r * 4 + c] = iA[r * 4 + 0] * P[0 * 4 + c] + iA[r * 4 + 1] * P[1 * 4 + c] +
                           iA[r * 4 + 2] * P[2 * 4 + c] + iA[r * 4 + 3] * P[3 * 4 + c];
    float rm = 1.0f / M[0];

    size_t pix = (size_t)(tileY * TH + ly) * w + tileX * TW + lx;
    float* op = featout + (size_t)b * cpb * hw + pix;
    op[0] = inten;
    #pragma unroll
    for (int k = 0; k < 16; k++) op[(size_t)(k + 1) * hw] = M[k] * rm;
}

// ---------------------------------------------------------------------------
// Plain per-pixel features (no pool) for the tiny 32x32 level.
// ---------------------------------------------------------------------------
__global__ __launch_bounds__(256) void feat_kernel(
        const float* __restrict__ in, float* __restrict__ out, int h, int w) {
    int hw = h * w;
    int npix = NB * hw;
    int idx = blockIdx.x * blockDim.x + threadIdx.x;
    if (idx >= npix) return;
    int b = idx / hw;
    int p = idx - b * hw;
    const float* px = in + (size_t)b * NC * hw + p;

    float Iv[16], tmp[16], iA[16], iW[16];
    #pragma unroll
    for (int k = 0; k < 16; k++) Iv[k] = px[(size_t)k * hw];
    #pragma unroll
    for (int k = 0; k < 16; k++) tmp[k] = px[(size_t)(16 + k) * hw];
    inv4x4(tmp, iA);
    #pragma unroll
    for (int k = 0; k < 16; k++) tmp[k] = px[(size_t)(32 + k) * hw];
    inv4x4(tmp, iW);

    float T[16];
    #pragma unroll
    for (int r = 0; r < 4; r++)
        #pragma unroll
        for (int c = 0; c < 4; c++)
            T[r * 4 + c] = iA[r * 4 + 0] * Iv[0 + c] + iA[r * 4 + 1] * Iv[4 + c] +
                           iA[r * 4 + 2] * Iv[8 + c] + iA[r * 4 + 3] * Iv[12 + c];
    float M[16];
    #pragma unroll
    for (int r = 0; r < 4; r++)
        #pragma unroll
        for (int c = 0; c < 4; c++)
            M[r * 4 + c] = T[r * 4 + 0] * iW[0 * 4 + c] + T[r * 4 + 1] * iW[1 * 4 + c] +
                           T[r * 4 + 2] * iW[2 * 4 + c] + T[r * 4 + 3] * iW[3 * 4 + c];
    float rm = 1.0f / M[0];

    float inten = 0.f;
    #pragma unroll
    for (int k = 0; k < 16; k++) inten += Iv[k];
    inten *= (1.0f / 16.0f);

    float* op = out + (size_t)b * NCH * hw + p;
    op[0] = inten;
    #pragma unroll
    for (int k = 0; k < 16; k++) op[(size_t)(k + 1) * hw] = M[k] * rm;
}

// ---------------------------------------------------------------------------
// QUAD bilinear upsample (align_corners=True), both levels -> out ch 17..50.
// Each thread owns a 1x4 output quad. The 4 px span <1 input px (scale<1), so
// their x-neighbors lie in {xlo, xlo+1, xlo+2}: per channel do 6 loads +
// 3 shared row-lerps, 4 col-lerps, ONE float4 store (16B/lane, G13).
// Arithmetic identical to reference (row-lerp then col-lerp).
// ---------------------------------------------------------------------------
__global__ __launch_bounds__(256) void upsample_quad_kernel(
        const float* __restrict__ feat1, const float* __restrict__ feat2,
        float* __restrict__ out) {
    int idx = blockIdx.x * blockDim.x + threadIdx.x;   // NB*H0*(W0/4) = 262144
    int q = idx & 127;            // quad col: X = 4q..4q+3
    int Y = (idx >> 7) & 511;
    int b = idx >> 16;            // 0..3

    const float* feats[2] = {feat1, feat2};
    const int dims[2] = {128, 32};
    const int choffs[2] = {17, 34};

    #pragma unroll
    for (int l = 0; l < 2; l++) {
        int h = dims[l];                       // == w (square)
        float s = (float)(h - 1) / (float)(H0 - 1);
        float yf = (float)Y * s;
        int y0 = (int)yf;
        if (y0 > h - 1) y0 = h - 1;
        int y1 = min(y0 + 1, h - 1);
        float fy = yf - (float)y0;

        float xf0 = (float)(4 * q) * s;
        int xlo = (int)xf0;
        if (xlo > h - 1) xlo = h - 1;
        int xi1 = min(xlo + 1, h - 1);
        int xi2 = min(xlo + 2, h - 1);

        int o0[4], o1[4];
        float fx[4];
        #pragma unroll
        for (int j = 0; j < 4; j++) {
            float xf = (float)(4 * q + j) * s;
            int x0 = (int)xf;
            if (x0 > h - 1) x0 = h - 1;
            fx[j] = xf - (float)x0;
            o0[j] = x0 - xlo;                       // 0 or 1
            o1[j] = min(x0 + 1, h - 1) - xlo;       // 1 or 2 (1 if clamped)
        }

        const float* fb = feats[l] + (size_t)b * NCH * h * h;
        float* ob = out + ((size_t)b * OUTC + choffs[l]) * (size_t)HW
                  + (size_t)Y * W0 + 4 * q;
        for (int c = 0; c < NCH; c++) {
            const float* r0 = fb + (size_t)c * h * h + (size_t)y0 * h;
            const float* r1 = fb + (size_t)c * h * h + (size_t)y1 * h;
            float rl0 = r0[xlo] * (1.f - fy) + r1[xlo] * fy;
            float rl1 = r0[xi1] * (1.f - fy) + r1[xi1] * fy;
            float rl2 = r0[xi2] * (1.f - fy) + r1[xi2] * fy;
            float4 o;
            float vals[4];
            #pragma unroll
            for (int j = 0; j < 4; j++) {
                float a  = (o0[j] == 0) ? rl0 : rl1;
                float bb = (o1[j] == 1) ? rl1 : rl2;
                vals[j] = a * (1.f - fx[j]) + bb * fx[j];
            }
            o.x = vals[0]; o.y = vals[1]; o.z = vals[2]; o.w = vals[3];
            *reinterpret_cast<float4*>(ob + (size_t)c * HW) = o;
        }
    }
}

extern "C" void kernel_launch(void* const* d_in, const int* in_sizes, int n_in,
                              void* d_out, int out_size, void* d_ws, size_t ws_size,
                              hipStream_t stream) {
    const float* x = (const float*)d_in[0];
    float* out = (float*)d_out;
    float* ws = (float*)d_ws;

    // workspace layout (floats)
    float* pool1 = ws;                                            // 4*48*128*128
    float* pool2 = pool1 + (size_t)NB * NC * 128 * 128;           // 4*48*32*32
    float* feat1 = pool2 + (size_t)NB * NC * 32 * 32;             // 4*17*128*128
    float* feat2 = feat1 + (size_t)NB * NCH * 128 * 128;          // 4*17*32*32

    // level 0: features -> out ch 0..16 (cpb=51), pool -> pool1. x read once.
    {
        int blocks = NB * (512 / TW) * (512 / TH);   // 4096
        feat_pool_lds<true><<<blocks, 256, 0, stream>>>(x, out, pool1, 512, 512, OUTC);
    }
    // level 1: features -> feat1 (cpb=17), pool -> pool2
    {
        int blocks = NB * (128 / TW) * (128 / TH);   // 256
        feat_pool_lds<true><<<blocks, 256, 0, stream>>>(pool1, feat1, pool2, 128, 128, NCH);
    }
    // level 2: features only -> feat2
    {
        int t = NB * 32 * 32;
        feat_kernel<<<(t + 255) / 256, 256, 0, stream>>>(pool2, feat2, 32, 32);
    }
    // upsample both levels -> out ch 17..50 (quad threads: NB*H0*W0/4)
    {
        int t = NB * H0 * (W0 / 4);                  // 262144 -> 1024 blocks
        upsample_quad_kernel<<<t / 256, 256, 0, stream>>>(feat1, feat2, out);
    }
}

// Round 12
// 104.483 us; speedup vs baseline: 1.2429x; 1.2429x over previous
//
#include <hip/hip_runtime.h>
#include <hip/hip_bf16.h>

#define NB 4
#define NC 48
#define H0 512
#define W0 512
#define HW (H0 * W0)
#define NCH 17   // 1 intensity + 16 mueller
#define OUTC 51  // 17 * 3 levels
#define TW 64    // tile width  (one wave row = one 1KB DMA per channel)
#define TH 4     // tile height (= pool window height)
#define SROW 260 // LDS row stride in floats: 1040B = 16B-aligned, +4 bank stagger

typedef const float __attribute__((address_space(1))) f32g;
typedef float __attribute__((address_space(3))) f32l;

// ---------------------------------------------------------------------------
// 4x4 inverse via adjugate (row-major).
// ---------------------------------------------------------------------------
__device__ __forceinline__ void inv4x4(const float* m, float* o) {
    float inv[16];
    inv[0]  =  m[5]*m[10]*m[15] - m[5]*m[11]*m[14] - m[9]*m[6]*m[15] + m[9]*m[7]*m[14] + m[13]*m[6]*m[11] - m[13]*m[7]*m[10];
    inv[4]  = -m[4]*m[10]*m[15] + m[4]*m[11]*m[14] + m[8]*m[6]*m[15] - m[8]*m[7]*m[14] - m[12]*m[6]*m[11] + m[12]*m[7]*m[10];
    inv[8]  =  m[4]*m[9]*m[15]  - m[4]*m[11]*m[13] - m[8]*m[5]*m[15] + m[8]*m[7]*m[13] + m[12]*m[5]*m[11] - m[12]*m[7]*m[9];
    inv[12] = -m[4]*m[9]*m[14]  + m[4]*m[10]*m[13] + m[8]*m[5]*m[14] - m[8]*m[6]*m[13] - m[12]*m[5]*m[10] + m[12]*m[6]*m[9];
    inv[1]  = -m[1]*m[10]*m[15] + m[1]*m[11]*m[14] + m[9]*m[2]*m[15] - m[9]*m[3]*m[14] - m[13]*m[2]*m[11] + m[13]*m[3]*m[10];
    inv[5]  =  m[0]*m[10]*m[15] - m[0]*m[11]*m[14] - m[8]*m[2]*m[15] + m[8]*m[3]*m[14] + m[12]*m[2]*m[11] - m[12]*m[3]*m[10];
    inv[9]  = -m[0]*m[9]*m[15]  + m[0]*m[11]*m[13] + m[8]*m[1]*m[15] - m[8]*m[3]*m[13] - m[12]*m[1]*m[11] + m[12]*m[3]*m[9];
    inv[13] =  m[0]*m[9]*m[14]  - m[0]*m[10]*m[13] - m[8]*m[1]*m[14] + m[8]*m[2]*m[13] + m[12]*m[1]*m[10] - m[12]*m[2]*m[9];
    inv[2]  =  m[1]*m[6]*m[15]  - m[1]*m[7]*m[14]  - m[5]*m[2]*m[15] + m[5]*m[3]*m[14] + m[13]*m[2]*m[7]  - m[13]*m[3]*m[6];
    inv[6]  = -m[0]*m[6]*m[15]  + m[0]*m[7]*m[14]  + m[4]*m[2]*m[15] - m[4]*m[3]*m[14] - m[12]*m[2]*m[7]  + m[12]*m[3]*m[6];
    inv[10] =  m[0]*m[5]*m[15]  - m[0]*m[7]*m[13]  - m[4]*m[1]*m[15] + m[4]*m[3]*m[13] + m[12]*m[1]*m[7]  - m[12]*m[3]*m[5];
    inv[14] = -m[0]*m[5]*m[14]  + m[0]*m[6]*m[13]  + m[4]*m[1]*m[14] - m[4]*m[2]*m[13] - m[12]*m[1]*m[6]  + m[12]*m[2]*m[5];
    inv[3]  = -m[1]*m[6]*m[11]  + m[1]*m[7]*m[10]  + m[5]*m[2]*m[11] - m[5]*m[3]*m[10] - m[9]*m[2]*m[7]   + m[9]*m[3]*m[6];
    inv[7]  =  m[0]*m[6]*m[11]  - m[0]*m[7]*m[10]  - m[4]*m[2]*m[11] + m[4]*m[3]*m[10] + m[8]*m[2]*m[7]   - m[8]*m[3]*m[6];
    inv[11] = -m[0]*m[5]*m[11]  + m[0]*m[7]*m[9]   + m[4]*m[1]*m[11] - m[4]*m[3]*m[9]  - m[8]*m[1]*m[7]   + m[8]*m[3]*m[5];
    inv[15] =  m[0]*m[5]*m[10]  - m[0]*m[6]*m[9]   - m[4]*m[1]*m[10] + m[4]*m[2]*m[9]  + m[8]*m[1]*m[6]   - m[8]*m[2]*m[5];
    float det = m[0]*inv[0] + m[1]*inv[4] + m[2]*inv[8] + m[3]*inv[12];
    float rd = 1.0f / det;
    #pragma unroll
    for (int i = 0; i < 16; i++) o[i] = inv[i] * rd;
}

// ---------------------------------------------------------------------------
// Fused Mueller features + optional 4x4 maxpool, 3-phase LDS (16ch at a time).
// Round-9 structure (best: 113.9us) + two additions:
//  (a) XCD-chunk block swizzle: XCD k gets a CONTIGUOUS slab of tiles, so its
//      L2 streams contiguous memory -> long HBM bursts instead of 8 XCDs
//      interleaving 256B fragments. Bijective since gridDim.x % 8 == 0.
//  (b) non-temporal stores for all streaming outputs (no write-allocate).
// ---------------------------------------------------------------------------
template <bool POOL>
__global__ __launch_bounds__(256, 8) void feat_pool_lds(
        const float* __restrict__ in, float* __restrict__ featout,
        float* __restrict__ poolout, int h, int w, int cpb) {
    __shared__ float s[16][SROW];

    int tilesX = w / TW;
    int tilesY = h / TH;
    // (a) XCD-aware swizzle: default dispatch is round-robin (XCD = bid % 8);
    // remap so XCD k processes contiguous tile range [k*chunk, (k+1)*chunk).
    int bid = blockIdx.x;
    int chunk = gridDim.x >> 3;
    int tile = (bid & 7) * chunk + (bid >> 3);

    int b = tile / (tilesX * tilesY);
    int trem = tile - b * (tilesX * tilesY);
    int tileY = trem / tilesX;
    int tileX = trem - tileY * tilesX;

    int tid = threadIdx.x;
    int ly = tid >> 6;          // wave id 0..3
    int lx = tid & 63;          // lane 0..63
    int hw = h * w;
    int ho = h >> 2, wo = w >> 2;

    // per-lane DMA source: lane l covers tile row (l>>4), cols (l&15)*4 .. +3
    const float* dmasrc = in + (size_t)b * NC * hw
                        + (size_t)(tileY * TH + (lx >> 4)) * w
                        + tileX * TW + (lx & 15) * 4;

    auto STAGE = [&](int ch0) {
        #pragma unroll
        for (int kk = 0; kk < 4; kk++) {
            int k = ly * 4 + kk;
            __builtin_amdgcn_global_load_lds((f32g*)(dmasrc + (size_t)(ch0 + k) * hw),
                                             (f32l*)&s[k][0], 16, 0, 0);
        }
    };
    auto POOLG = [&](int ch0) {
        if (POOL) {
            int k = tid >> 4;
            int c = tid & 15;
            float m = -INFINITY;
            #pragma unroll
            for (int r = 0; r < TH; r++)
                #pragma unroll
                for (int j = 0; j < 4; j++)
                    m = fmaxf(m, s[k][r * TW + c * 4 + j]);
            __builtin_nontemporal_store(m,
                &poolout[((size_t)(b * NC + ch0 + k) * ho + tileY) * wo + tileX * 16 + c]);
        }
    };

    float tmp[16];

    // ---- phase 1: W -> iW ----
    STAGE(32);
    __syncthreads();
    POOLG(32);
    float iW[16];
    #pragma unroll
    for (int k = 0; k < 16; k++) tmp[k] = s[k][tid];
    inv4x4(tmp, iW);
    __syncthreads();

    // ---- phase 2: I -> P = I*iW, intensity ----
    STAGE(0);
    __syncthreads();
    POOLG(0);
    float P[16];
    float inten = 0.f;
    #pragma unroll
    for (int r = 0; r < 4; r++) {
        float i0 = s[r * 4 + 0][tid], i1 = s[r * 4 + 1][tid],
              i2 = s[r * 4 + 2][tid], i3 = s[r * 4 + 3][tid];
        inten += i0 + i1 + i2 + i3;
        #pragma unroll
        for (int c = 0; c < 4; c++)
            P[r * 4 + c] = i0 * iW[0 * 4 + c] + i1 * iW[1 * 4 + c] +
                           i2 * iW[2 * 4 + c] + i3 * iW[3 * 4 + c];
    }
    inten *= (1.0f / 16.0f);
    __syncthreads();

    // ---- phase 3: A -> iA, M = iA*P, store ----
    STAGE(16);
    __syncthreads();
    POOLG(16);
    float iA[16];
    #pragma unroll
    for (int k = 0; k < 16; k++) tmp[k] = s[k][tid];
    inv4x4(tmp, iA);

    float M[16];
    #pragma unroll
    for (int r = 0; r < 4; r++)
        #pragma unroll
        for (int c = 0; c < 4; c++)
            M[r * 4 + c] = iA[r * 4 + 0] * P[0 * 4 + c] + iA[r * 4 + 1] * P[1 * 4 + c] +
                           iA[r * 4 + 2] * P[2 * 4 + c] + iA[r * 4 + 3] * P[3 * 4 + c];
    float rm = 1.0f / M[0];

    size_t pix = (size_t)(tileY * TH + ly) * w + tileX * TW + lx;
    float* op = featout + (size_t)b * cpb * hw + pix;
    __builtin_nontemporal_store(inten, op);
    #pragma unroll
    for (int k = 0; k < 16; k++)
        __builtin_nontemporal_store(M[k] * rm, op + (size_t)(k + 1) * hw);
}

// ---------------------------------------------------------------------------
// Plain per-pixel features (no pool) for the tiny 32x32 level.
// ---------------------------------------------------------------------------
__global__ __launch_bounds__(256) void feat_kernel(
        const float* __restrict__ in, float* __restrict__ out, int h, int w) {
    int hw = h * w;
    int npix = NB * hw;
    int idx = blockIdx.x * blockDim.x + threadIdx.x;
    if (idx >= npix) return;
    int b = idx / hw;
    int p = idx - b * hw;
    const float* px = in + (size_t)b * NC * hw + p;

    float Iv[16], tmp[16], iA[16], iW[16];
    #pragma unroll
    for (int k = 0; k < 16; k++) Iv[k] = px[(size_t)k * hw];
    #pragma unroll
    for (int k = 0; k < 16; k++) tmp[k] = px[(size_t)(16 + k) * hw];
    inv4x4(tmp, iA);
    #pragma unroll
    for (int k = 0; k < 16; k++) tmp[k] = px[(size_t)(32 + k) * hw];
    inv4x4(tmp, iW);

    float T[16];
    #pragma unroll
    for (int r = 0; r < 4; r++)
        #pragma unroll
        for (int c = 0; c < 4; c++)
            T[r * 4 + c] = iA[r * 4 + 0] * Iv[0 + c] + iA[r * 4 + 1] * Iv[4 + c] +
                           iA[r * 4 + 2] * Iv[8 + c] + iA[r * 4 + 3] * Iv[12 + c];
    float M[16];
    #pragma unroll
    for (int r = 0; r < 4; r++)
        #pragma unroll
        for (int c = 0; c < 4; c++)
            M[r * 4 + c] = T[r * 4 + 0] * iW[0 * 4 + c] + T[r * 4 + 1] * iW[1 * 4 + c] +
                           T[r * 4 + 2] * iW[2 * 4 + c] + T[r * 4 + 3] * iW[3 * 4 + c];
    float rm = 1.0f / M[0];

    float inten = 0.f;
    #pragma unroll
    for (int k = 0; k < 16; k++) inten += Iv[k];
    inten *= (1.0f / 16.0f);

    float* op = out + (size_t)b * NCH * hw + p;
    op[0] = inten;
    #pragma unroll
    for (int k = 0; k < 16; k++) op[(size_t)(k + 1) * hw] = M[k] * rm;
}

// ---------------------------------------------------------------------------
// Bilinear upsample (align_corners=True) of BOTH pyramid levels to 512x512.
// (Round-9 version: measured at ~write-floor. nt stores added.)
// ---------------------------------------------------------------------------
__global__ __launch_bounds__(256) void upsample_both_kernel(
        const float* __restrict__ feat1, const float* __restrict__ feat2,
        float* __restrict__ out) {
    int idx = blockIdx.x * blockDim.x + threadIdx.x;
    int total = NB * H0 * W0;
    if (idx >= total) return;
    int X = idx % W0;
    int Y = (idx / W0) % H0;
    int b = idx / (W0 * H0);

    const float* feats[2] = {feat1, feat2};
    const int dims[2] = {128, 32};
    const int choffs[2] = {17, 34};

    #pragma unroll
    for (int l = 0; l < 2; l++) {
        int h = dims[l], w = dims[l];
        float sy = (float)(h - 1) / (float)(H0 - 1);
        float sx = (float)(w - 1) / (float)(W0 - 1);
        float yf = (float)Y * sy;
        float xf = (float)X * sx;
        int y0 = (int)yf;
        int x0 = (int)xf;
        if (y0 > h - 1) y0 = h - 1;
        if (x0 > w - 1) x0 = w - 1;
        int y1 = min(y0 + 1, h - 1);
        int x1 = min(x0 + 1, w - 1);
        float fy = yf - (float)y0;
        float fx = xf - (float)x0;

        const float* fb = feats[l] + (size_t)b * NCH * h * w;
        float* ob = out + ((size_t)b * OUTC + choffs[l]) * (size_t)HW + (size_t)Y * W0 + X;
        for (int c = 0; c < NCH; c++) {
            const float* fc = fb + (size_t)c * h * w;
            float v00 = fc[(size_t)y0 * w + x0];
            float v01 = fc[(size_t)y0 * w + x1];
            float v10 = fc[(size_t)y1 * w + x0];
            float v11 = fc[(size_t)y1 * w + x1];
            float a  = v00 * (1.f - fy) + v10 * fy;
            float bb = v01 * (1.f - fy) + v11 * fy;
            __builtin_nontemporal_store(a * (1.f - fx) + bb * fx, ob + (size_t)c * HW);
        }
    }
}

extern "C" void kernel_launch(void* const* d_in, const int* in_sizes, int n_in,
                              void* d_out, int out_size, void* d_ws, size_t ws_size,
                              hipStream_t stream) {
    const float* x = (const float*)d_in[0];
    float* out = (float*)d_out;
    float* ws = (float*)d_ws;

    // workspace layout (floats)
    float* pool1 = ws;                                            // 4*48*128*128
    float* pool2 = pool1 + (size_t)NB * NC * 128 * 128;           // 4*48*32*32
    float* feat1 = pool2 + (size_t)NB * NC * 32 * 32;             // 4*17*128*128
    float* feat2 = feat1 + (size_t)NB * NCH * 128 * 128;          // 4*17*32*32

    // level 0: features -> out ch 0..16 (cpb=51), pool -> pool1. x read once.
    {
        int blocks = NB * (512 / TW) * (512 / TH);   // 4096 (divisible by 8)
        feat_pool_lds<true><<<blocks, 256, 0, stream>>>(x, out, pool1, 512, 512, OUTC);
    }
    // level 1: features -> feat1 (cpb=17), pool -> pool2
    {
        int blocks = NB * (128 / TW) * (128 / TH);   // 256 (divisible by 8)
        feat_pool_lds<true><<<blocks, 256, 0, stream>>>(pool1, feat1, pool2, 128, 128, NCH);
    }
    // level 2: features only -> feat2
    {
        int t = NB * 32 * 32;
        feat_kernel<<<(t + 255) / 256, 256, 0, stream>>>(pool2, feat2, 32, 32);
    }
    // upsample both levels -> out ch 17..50
    {
        int t = NB * H0 * W0;
        upsample_both_kernel<<<(t + 255) / 256, 256, 0, stream>>>(feat1, feat2, out);
    }
}

// Round 13
// 85.049 us; speedup vs baseline: 1.5269x; 1.2285x over previous
//
#include <hip/hip_runtime.h>
#include <hip/hip_bf16.h>

#define NB 4
#define NC 48
#define H0 512
#define W0 512
#define HW (H0 * W0)
#define NCH 17   // 1 intensity + 16 mueller
#define OUTC 51  // 17 * 3 levels
#define TW 64    // tile width  (one wave row = one 1KB DMA per channel)
#define TH 4     // tile height (= pool window height)
#define SROW 260 // LDS row stride in floats: 1040B = 16B-aligned, +4 bank stagger

typedef const float __attribute__((address_space(1))) f32g;
typedef float __attribute__((address_space(3))) f32l;

// ---------------------------------------------------------------------------
// 4x4 inverse via adjugate (row-major).
// ---------------------------------------------------------------------------
__device__ __forceinline__ void inv4x4(const float* m, float* o) {
    float inv[16];
    inv[0]  =  m[5]*m[10]*m[15] - m[5]*m[11]*m[14] - m[9]*m[6]*m[15] + m[9]*m[7]*m[14] + m[13]*m[6]*m[11] - m[13]*m[7]*m[10];
    inv[4]  = -m[4]*m[10]*m[15] + m[4]*m[11]*m[14] + m[8]*m[6]*m[15] - m[8]*m[7]*m[14] - m[12]*m[6]*m[11] + m[12]*m[7]*m[10];
    inv[8]  =  m[4]*m[9]*m[15]  - m[4]*m[11]*m[13] - m[8]*m[5]*m[15] + m[8]*m[7]*m[13] + m[12]*m[5]*m[11] - m[12]*m[7]*m[9];
    inv[12] = -m[4]*m[9]*m[14]  + m[4]*m[10]*m[13] + m[8]*m[5]*m[14] - m[8]*m[6]*m[13] - m[12]*m[5]*m[10] + m[12]*m[6]*m[9];
    inv[1]  = -m[1]*m[10]*m[15] + m[1]*m[11]*m[14] + m[9]*m[2]*m[15] - m[9]*m[3]*m[14] - m[13]*m[2]*m[11] + m[13]*m[3]*m[10];
    inv[5]  =  m[0]*m[10]*m[15] - m[0]*m[11]*m[14] - m[8]*m[2]*m[15] + m[8]*m[3]*m[14] + m[12]*m[2]*m[11] - m[12]*m[3]*m[10];
    inv[9]  = -m[0]*m[9]*m[15]  + m[0]*m[11]*m[13] + m[8]*m[1]*m[15] - m[8]*m[3]*m[13] - m[12]*m[1]*m[11] + m[12]*m[3]*m[9];
    inv[13] =  m[0]*m[9]*m[14]  - m[0]*m[10]*m[13] - m[8]*m[1]*m[14] + m[8]*m[2]*m[13] + m[12]*m[1]*m[10] - m[12]*m[2]*m[9];
    inv[2]  =  m[1]*m[6]*m[15]  - m[1]*m[7]*m[14]  - m[5]*m[2]*m[15] + m[5]*m[3]*m[14] + m[13]*m[2]*m[7]  - m[13]*m[3]*m[6];
    inv[6]  = -m[0]*m[6]*m[15]  + m[0]*m[7]*m[14]  + m[4]*m[2]*m[15] - m[4]*m[3]*m[14] - m[12]*m[2]*m[7]  + m[12]*m[3]*m[6];
    inv[10] =  m[0]*m[5]*m[15]  - m[0]*m[7]*m[13]  - m[4]*m[1]*m[15] + m[4]*m[3]*m[13] + m[12]*m[1]*m[7]  - m[12]*m[3]*m[5];
    inv[14] = -m[0]*m[5]*m[14]  + m[0]*m[6]*m[13]  + m[4]*m[1]*m[14] - m[4]*m[2]*m[13] - m[12]*m[1]*m[6]  + m[12]*m[2]*m[5];
    inv[3]  = -m[1]*m[6]*m[11]  + m[1]*m[7]*m[10]  + m[5]*m[2]*m[11] - m[5]*m[3]*m[10] - m[9]*m[2]*m[7]   + m[9]*m[3]*m[6];
    inv[7]  =  m[0]*m[6]*m[11]  - m[0]*m[7]*m[10]  - m[4]*m[2]*m[11] + m[4]*m[3]*m[10] + m[8]*m[2]*m[7]   - m[8]*m[3]*m[6];
    inv[11] = -m[0]*m[5]*m[11]  + m[0]*m[7]*m[9]   + m[4]*m[1]*m[11] - m[4]*m[3]*m[9]  - m[8]*m[1]*m[7]   + m[8]*m[3]*m[5];
    inv[15] =  m[0]*m[5]*m[10]  - m[0]*m[6]*m[9]   - m[4]*m[1]*m[10] + m[4]*m[2]*m[9]  + m[8]*m[1]*m[6]   - m[8]*m[2]*m[5];
    float det = m[0]*inv[0] + m[1]*inv[4] + m[2]*inv[8] + m[3]*inv[12];
    float rd = 1.0f / det;
    #pragma unroll
    for (int i = 0; i < 16; i++) o[i] = inv[i] * rd;
}

// ---------------------------------------------------------------------------
// Fused Mueller features + optional 4x4 maxpool, 3-phase LDS (16ch at a time),
// XCD-chunk swizzled. nt policy is SELECTIVE:
//   - featout stores: nt only when NTOUT (level 0 -> d_out, never re-read).
//     L1/L2 featout goes to ws and is re-read by upsample -> keep cacheable.
//   - pool stores: always cacheable (pool1/pool2 are re-read by next level).
// ---------------------------------------------------------------------------
template <bool POOL, bool NTOUT>
__global__ __launch_bounds__(256, 8) void feat_pool_lds(
        const float* __restrict__ in, float* __restrict__ featout,
        float* __restrict__ poolout, int h, int w, int cpb) {
    __shared__ float s[16][SROW];

    int tilesX = w / TW;
    int tilesY = h / TH;
    // XCD-aware swizzle: XCD k (= bid%8 at dispatch) gets contiguous tile slab.
    int bid = blockIdx.x;
    int chunk = gridDim.x >> 3;
    int tile = (bid & 7) * chunk + (bid >> 3);

    int b = tile / (tilesX * tilesY);
    int trem = tile - b * (tilesX * tilesY);
    int tileY = trem / tilesX;
    int tileX = trem - tileY * tilesX;

    int tid = threadIdx.x;
    int ly = tid >> 6;          // wave id 0..3
    int lx = tid & 63;          // lane 0..63
    int hw = h * w;
    int ho = h >> 2, wo = w >> 2;

    // per-lane DMA source: lane l covers tile row (l>>4), cols (l&15)*4 .. +3
    const float* dmasrc = in + (size_t)b * NC * hw
                        + (size_t)(tileY * TH + (lx >> 4)) * w
                        + tileX * TW + (lx & 15) * 4;

    auto STAGE = [&](int ch0) {
        #pragma unroll
        for (int kk = 0; kk < 4; kk++) {
            int k = ly * 4 + kk;
            __builtin_amdgcn_global_load_lds((f32g*)(dmasrc + (size_t)(ch0 + k) * hw),
                                             (f32l*)&s[k][0], 16, 0, 0);
        }
    };
    auto POOLG = [&](int ch0) {
        if (POOL) {
            int k = tid >> 4;
            int c = tid & 15;
            float m = -INFINITY;
            #pragma unroll
            for (int r = 0; r < TH; r++)
                #pragma unroll
                for (int j = 0; j < 4; j++)
                    m = fmaxf(m, s[k][r * TW + c * 4 + j]);
            // cacheable: consumed by the next pyramid level shortly after
            poolout[((size_t)(b * NC + ch0 + k) * ho + tileY) * wo + tileX * 16 + c] = m;
        }
    };

    float tmp[16];

    // ---- phase 1: W -> iW ----
    STAGE(32);
    __syncthreads();
    POOLG(32);
    float iW[16];
    #pragma unroll
    for (int k = 0; k < 16; k++) tmp[k] = s[k][tid];
    inv4x4(tmp, iW);
    __syncthreads();

    // ---- phase 2: I -> P = I*iW, intensity ----
    STAGE(0);
    __syncthreads();
    POOLG(0);
    float P[16];
    float inten = 0.f;
    #pragma unroll
    for (int r = 0; r < 4; r++) {
        float i0 = s[r * 4 + 0][tid], i1 = s[r * 4 + 1][tid],
              i2 = s[r * 4 + 2][tid], i3 = s[r * 4 + 3][tid];
        inten += i0 + i1 + i2 + i3;
        #pragma unroll
        for (int c = 0; c < 4; c++)
            P[r * 4 + c] = i0 * iW[0 * 4 + c] + i1 * iW[1 * 4 + c] +
                           i2 * iW[2 * 4 + c] + i3 * iW[3 * 4 + c];
    }
    inten *= (1.0f / 16.0f);
    __syncthreads();

    // ---- phase 3: A -> iA, M = iA*P, store ----
    STAGE(16);
    __syncthreads();
    POOLG(16);
    float iA[16];
    #pragma unroll
    for (int k = 0; k < 16; k++) tmp[k] = s[k][tid];
    inv4x4(tmp, iA);

    float M[16];
    #pragma unroll
    for (int r = 0; r < 4; r++)
        #pragma unroll
        for (int c = 0; c < 4; c++)
            M[r * 4 + c] = iA[r * 4 + 0] * P[0 * 4 + c] + iA[r * 4 + 1] * P[1 * 4 + c] +
                           iA[r * 4 + 2] * P[2 * 4 + c] + iA[r * 4 + 3] * P[3 * 4 + c];
    float rm = 1.0f / M[0];

    size_t pix = (size_t)(tileY * TH + ly) * w + tileX * TW + lx;
    float* op = featout + (size_t)b * cpb * hw + pix;
    if (NTOUT) {
        __builtin_nontemporal_store(inten, op);
        #pragma unroll
        for (int k = 0; k < 16; k++)
            __builtin_nontemporal_store(M[k] * rm, op + (size_t)(k + 1) * hw);
    } else {
        op[0] = inten;
        #pragma unroll
        for (int k = 0; k < 16; k++) op[(size_t)(k + 1) * hw] = M[k] * rm;
    }
}

// ---------------------------------------------------------------------------
// Plain per-pixel features (no pool) for the tiny 32x32 level.
// ---------------------------------------------------------------------------
__global__ __launch_bounds__(256) void feat_kernel(
        const float* __restrict__ in, float* __restrict__ out, int h, int w) {
    int hw = h * w;
    int npix = NB * hw;
    int idx = blockIdx.x * blockDim.x + threadIdx.x;
    if (idx >= npix) return;
    int b = idx / hw;
    int p = idx - b * hw;
    const float* px = in + (size_t)b * NC * hw + p;

    float Iv[16], tmp[16], iA[16], iW[16];
    #pragma unroll
    for (int k = 0; k < 16; k++) Iv[k] = px[(size_t)k * hw];
    #pragma unroll
    for (int k = 0; k < 16; k++) tmp[k] = px[(size_t)(16 + k) * hw];
    inv4x4(tmp, iA);
    #pragma unroll
    for (int k = 0; k < 16; k++) tmp[k] = px[(size_t)(32 + k) * hw];
    inv4x4(tmp, iW);

    float T[16];
    #pragma unroll
    for (int r = 0; r < 4; r++)
        #pragma unroll
        for (int c = 0; c < 4; c++)
            T[r * 4 + c] = iA[r * 4 + 0] * Iv[0 + c] + iA[r * 4 + 1] * Iv[4 + c] +
                           iA[r * 4 + 2] * Iv[8 + c] + iA[r * 4 + 3] * Iv[12 + c];
    float M[16];
    #pragma unroll
    for (int r = 0; r < 4; r++)
        #pragma unroll
        for (int c = 0; c < 4; c++)
            M[r * 4 + c] = T[r * 4 + 0] * iW[0 * 4 + c] + T[r * 4 + 1] * iW[1 * 4 + c] +
                           T[r * 4 + 2] * iW[2 * 4 + c] + T[r * 4 + 3] * iW[3 * 4 + c];
    float rm = 1.0f / M[0];

    float inten = 0.f;
    #pragma unroll
    for (int k = 0; k < 16; k++) inten += Iv[k];
    inten *= (1.0f / 16.0f);

    float* op = out + (size_t)b * NCH * hw + p;
    op[0] = inten;
    #pragma unroll
    for (int k = 0; k < 16; k++) op[(size_t)(k + 1) * hw] = M[k] * rm;
}

// ---------------------------------------------------------------------------
// Bilinear upsample (align_corners=True) of BOTH pyramid levels to 512x512.
// nt stores (d_out never re-read); feat reads stay cacheable.
// ---------------------------------------------------------------------------
__global__ __launch_bounds__(256) void upsample_both_kernel(
        const float* __restrict__ feat1, const float* __restrict__ feat2,
        float* __restrict__ out) {
    int idx = blockIdx.x * blockDim.x + threadIdx.x;
    int total = NB * H0 * W0;
    if (idx >= total) return;
    int X = idx % W0;
    int Y = (idx / W0) % H0;
    int b = idx / (W0 * H0);

    const float* feats[2] = {feat1, feat2};
    const int dims[2] = {128, 32};
    const int choffs[2] = {17, 34};

    #pragma unroll
    for (int l = 0; l < 2; l++) {
        int h = dims[l], w = dims[l];
        float sy = (float)(h - 1) / (float)(H0 - 1);
        float sx = (float)(w - 1) / (float)(W0 - 1);
        float yf = (float)Y * sy;
        float xf = (float)X * sx;
        int y0 = (int)yf;
        int x0 = (int)xf;
        if (y0 > h - 1) y0 = h - 1;
        if (x0 > w - 1) x0 = w - 1;
        int y1 = min(y0 + 1, h - 1);
        int x1 = min(x0 + 1, w - 1);
        float fy = yf - (float)y0;
        float fx = xf - (float)x0;

        const float* fb = feats[l] + (size_t)b * NCH * h * w;
        float* ob = out + ((size_t)b * OUTC + choffs[l]) * (size_t)HW + (size_t)Y * W0 + X;
        for (int c = 0; c < NCH; c++) {
            const float* fc = fb + (size_t)c * h * w;
            float v00 = fc[(size_t)y0 * w + x0];
            float v01 = fc[(size_t)y0 * w + x1];
            float v10 = fc[(size_t)y1 * w + x0];
            float v11 = fc[(size_t)y1 * w + x1];
            float a  = v00 * (1.f - fy) + v10 * fy;
            float bb = v01 * (1.f - fy) + v11 * fy;
            __builtin_nontemporal_store(a * (1.f - fx) + bb * fx, ob + (size_t)c * HW);
        }
    }
}

extern "C" void kernel_launch(void* const* d_in, const int* in_sizes, int n_in,
                              void* d_out, int out_size, void* d_ws, size_t ws_size,
                              hipStream_t stream) {
    const float* x = (const float*)d_in[0];
    float* out = (float*)d_out;
    float* ws = (float*)d_ws;

    // workspace layout (floats)
    float* pool1 = ws;                                            // 4*48*128*128
    float* pool2 = pool1 + (size_t)NB * NC * 128 * 128;           // 4*48*32*32
    float* feat1 = pool2 + (size_t)NB * NC * 32 * 32;             // 4*17*128*128
    float* feat2 = feat1 + (size_t)NB * NCH * 128 * 128;          // 4*17*32*32

    // level 0: features -> out ch 0..16 (cpb=51, nt), pool -> pool1 (cacheable)
    {
        int blocks = NB * (512 / TW) * (512 / TH);   // 4096 (divisible by 8)
        feat_pool_lds<true, true><<<blocks, 256, 0, stream>>>(x, out, pool1, 512, 512, OUTC);
    }
    // level 1: features -> feat1 (cacheable), pool -> pool2 (cacheable)
    {
        int blocks = NB * (128 / TW) * (128 / TH);   // 256 (divisible by 8)
        feat_pool_lds<true, false><<<blocks, 256, 0, stream>>>(pool1, feat1, pool2, 128, 128, NCH);
    }
    // level 2: features only -> feat2
    {
        int t = NB * 32 * 32;
        feat_kernel<<<(t + 255) / 256, 256, 0, stream>>>(pool2, feat2, 32, 32);
    }
    // upsample both levels -> out ch 17..50
    {
        int t = NB * H0 * W0;
        upsample_both_kernel<<<(t + 255) / 256, 256, 0, stream>>>(feat1, feat2, out);
    }
}